// Round 6
// baseline (319.450 us; speedup 1.0000x reference)
//
#include <hip/hip_runtime.h>
#include <hip/hip_fp16.h>
#include <cstdint>

#define NEG_SLOPE 0.2f
#define SM_EPS 1e-16f
#define BN_EPS 1e-5f

struct alignas(8) half4v { __half2 lo, hi; };

// ---------- GEMM + fused attention coefficients, 4 rows/thread, fp16 G out ----------
template <int INC, int OUTC, int H>
__global__ __launch_bounds__(256) void gemm_k(const float* __restrict__ A,
                                              const float* __restrict__ W,
                                              const float* __restrict__ asrc,
                                              const float* __restrict__ adst,
                                              __half* __restrict__ G,
                                              float* __restrict__ als,
                                              float* __restrict__ ald, int nrows) {
  constexpr int TPR  = OUTC / 4;   // threads per row (32 or 16)
  constexpr int RS   = 256 / TPR;  // row slots (8 or 16)
  constexpr int ROWS = RS * 4;     // rows per block-iter (4 rows per thread)
  __shared__ float wl[INC * OUTC];                 // 64 KB (OUTC=128) / 32 KB
  __shared__ float hl[ROWS * INC];                 // 16 KB / 32 KB
  for (int i = threadIdx.x * 4; i < INC * OUTC; i += 1024)
    *(float4*)&wl[i] = *(const float4*)&W[i];
  int r  = threadIdx.x / TPR;
  int c0 = (threadIdx.x % TPR) * 4;
  float4 sv = *(const float4*)&asrc[c0];
  float4 dv = *(const float4*)&adst[c0];
  for (int base = blockIdx.x * ROWS; base < nrows; base += gridDim.x * ROWS) {
    __syncthreads();  // prev iter reads done (also orders first wl use)
    int limit = min(ROWS, nrows - base) * INC;
    for (int i = threadIdx.x * 4; i < limit; i += 1024)
      *(float4*)&hl[i] = *(const float4*)&A[(size_t)base * INC + i];
    __syncthreads();
    float acc[4][4];
#pragma unroll
    for (int q = 0; q < 4; q++)
#pragma unroll
      for (int c = 0; c < 4; c++) acc[q][c] = 0.f;
#pragma unroll 8
    for (int k = 0; k < INC; k++) {
      float4 wv = *(float4*)&wl[k * OUTC + c0];
#pragma unroll
      for (int q = 0; q < 4; q++) {
        float h = hl[(r + q * RS) * INC + k];
        acc[q][0] = fmaf(h, wv.x, acc[q][0]);
        acc[q][1] = fmaf(h, wv.y, acc[q][1]);
        acc[q][2] = fmaf(h, wv.z, acc[q][2]);
        acc[q][3] = fmaf(h, wv.w, acc[q][3]);
      }
    }
    float ps[4], pd[4];
#pragma unroll
    for (int q = 0; q < 4; q++) {
      int rq = base + r + q * RS;
      if (rq < nrows) {
        half4v hv;
        hv.lo = __floats2half2_rn(acc[q][0], acc[q][1]);
        hv.hi = __floats2half2_rn(acc[q][2], acc[q][3]);
        *(half4v*)&G[(size_t)rq * OUTC + c0] = hv;
      }
      ps[q] = acc[q][0] * sv.x + acc[q][1] * sv.y + acc[q][2] * sv.z + acc[q][3] * sv.w;
      pd[q] = acc[q][0] * dv.x + acc[q][1] * dv.y + acc[q][2] * dv.z + acc[q][3] * dv.w;
    }
#pragma unroll
    for (int o = 1; o < 16; o <<= 1) {
#pragma unroll
      for (int q = 0; q < 4; q++) {
        ps[q] += __shfl_xor(ps[q], o);
        pd[q] += __shfl_xor(pd[q], o);
      }
    }
    if ((threadIdx.x & 15) == 0) {
      int head = c0 >> 6;  // 0 for cols 0..63, 1 for 64..127 (always 0 if OUTC==64)
#pragma unroll
      for (int q = 0; q < 4; q++) {
        int rq = base + r + q * RS;
        if (rq < nrows) {
          als[(size_t)rq * H + head] = ps[q];
          ald[(size_t)rq * H + head] = pd[q];
        }
      }
    }
  }
}

// ---------- CSR build ----------
__global__ void deg_k(const int* __restrict__ dst, int E_, int n, int* __restrict__ deg) {
  int ET = E_ + n;
  for (int e = blockIdx.x * blockDim.x + threadIdx.x; e < ET; e += gridDim.x * blockDim.x) {
    int dN = (e < E_) ? dst[e] : (e - E_);
    atomicAdd(&deg[dN], 1);
  }
}

__global__ __launch_bounds__(1024) void scan1_k(const int* __restrict__ deg,
                                                int* __restrict__ incl,
                                                int* __restrict__ bsum, int n) {
  __shared__ int sm[1024];
  int i = blockIdx.x * 1024 + threadIdx.x;
  int v = (i < n) ? deg[i] : 0;
  sm[threadIdx.x] = v;
  __syncthreads();
#pragma unroll
  for (int o = 1; o < 1024; o <<= 1) {
    int t = (threadIdx.x >= o) ? sm[threadIdx.x - o] : 0;
    __syncthreads();
    sm[threadIdx.x] += t;
    __syncthreads();
  }
  if (i < n) incl[i] = sm[threadIdx.x];
  if (threadIdx.x == 1023) bsum[blockIdx.x] = sm[1023];
}

__global__ void scan2_k(int* __restrict__ bsum, int nb) {
  int lane = threadIdx.x;
  int v = (lane < nb) ? bsum[lane] : 0;
#pragma unroll
  for (int o = 1; o < 64; o <<= 1) {
    int t = __shfl_up(v, o);
    if (lane >= o) v += t;
  }
  if (lane < nb) bsum[lane] = v;
}

__global__ void scan3_k(const int* __restrict__ incl, const int* __restrict__ bsum,
                        const int* __restrict__ deg, int* __restrict__ rowptr,
                        int* __restrict__ cursor, int n) {
  int i = blockIdx.x * blockDim.x + threadIdx.x;
  if (i < n) {
    int blk = i >> 10;
    int off = blk ? bsum[blk - 1] : 0;
    int r = incl[i] + off;
    rowptr[i + 1] = r;
    cursor[i] = r - deg[i];
  }
  if (i == 0) rowptr[0] = 0;
}

__global__ void csr_fill_k(const int* __restrict__ src, const int* __restrict__ dst,
                           int E_, int n, int* __restrict__ cursor,
                           uint16_t* __restrict__ csr_src) {
  int ET = E_ + n;
  for (int e = blockIdx.x * blockDim.x + threadIdx.x; e < ET; e += gridDim.x * blockDim.x) {
    int sN = (e < E_) ? src[e] : (e - E_);
    int dN = (e < E_) ? dst[e] : (e - E_);
    int pos = atomicAdd(&cursor[dN], 1);
    __builtin_nontemporal_store((uint16_t)sN, &csr_src[pos]);
  }
}

// ---------- fused GAT aggregation (H=2), fp16 G gather, u16 csr ----------
__global__ __launch_bounds__(256) void gat_agg2_k(
    const int* __restrict__ rowptr, const uint16_t* __restrict__ csr_src,
    const float* __restrict__ als, const float* __restrict__ ald,
    const __half* __restrict__ G, const float* __restrict__ bias,
    const float* __restrict__ gamma, const float* __restrict__ beta,
    const float* __restrict__ mean, const float* __restrict__ var,
    float* __restrict__ out, int n) {
  int lane = threadIdx.x & 63;
  int wid  = (blockIdx.x * blockDim.x + threadIdx.x) >> 6;
  int nw   = (gridDim.x * blockDim.x) >> 6;
  for (int node = wid; node < n; node += nw) {
    int beg = rowptr[node];
    int deg = rowptr[node + 1] - beg;
    float2 adp = *(const float2*)&ald[(size_t)node * 2];
    float aAx = 0.f, aAy = 0.f, aBx = 0.f, aBy = 0.f;
    float aCx = 0.f, aCy = 0.f, aDx = 0.f, aDy = 0.f;
    if (deg <= 64) {
      int sl = 0;
      float p0 = 0.f, p1 = 0.f;
      if (lane < deg) {
        sl = csr_src[beg + lane];
        float2 ap = *(const float2*)&als[(size_t)sl * 2];
        float v0 = ap.x + adp.x, v1 = ap.y + adp.y;
        v0 = v0 > 0.f ? v0 : NEG_SLOPE * v0;
        v1 = v1 > 0.f ? v1 : NEG_SLOPE * v1;
        p0 = __expf(v0); p1 = __expf(v1);
      }
      float s0 = p0, s1 = p1;
#pragma unroll
      for (int o = 1; o < 64; o <<= 1) {
        s0 += __shfl_xor(s0, o);
        s1 += __shfl_xor(s1, o);
      }
      float a0 = p0 / (s0 + SM_EPS);
      float a1 = p1 / (s1 + SM_EPS);
      bool hi = (lane >= 32);
      int i = 0;
      for (; i + 4 <= deg; i += 4) {
        int sA = __shfl(sl, i), sB = __shfl(sl, i + 1);
        int sC = __shfl(sl, i + 2), sD = __shfl(sl, i + 3);
        float wA0 = __shfl(a0, i),     wA1 = __shfl(a1, i);
        float wB0 = __shfl(a0, i + 1), wB1 = __shfl(a1, i + 1);
        float wC0 = __shfl(a0, i + 2), wC1 = __shfl(a1, i + 2);
        float wD0 = __shfl(a0, i + 3), wD1 = __shfl(a1, i + 3);
        float wA = hi ? wA1 : wA0, wB = hi ? wB1 : wB0;
        float wC = hi ? wC1 : wC0, wD = hi ? wD1 : wD0;
        float2 gA = __half22float2(*(const __half2*)&G[(size_t)sA * 128 + 2 * lane]);
        float2 gB = __half22float2(*(const __half2*)&G[(size_t)sB * 128 + 2 * lane]);
        float2 gC = __half22float2(*(const __half2*)&G[(size_t)sC * 128 + 2 * lane]);
        float2 gD = __half22float2(*(const __half2*)&G[(size_t)sD * 128 + 2 * lane]);
        aAx = fmaf(wA, gA.x, aAx); aAy = fmaf(wA, gA.y, aAy);
        aBx = fmaf(wB, gB.x, aBx); aBy = fmaf(wB, gB.y, aBy);
        aCx = fmaf(wC, gC.x, aCx); aCy = fmaf(wC, gC.y, aCy);
        aDx = fmaf(wD, gD.x, aDx); aDy = fmaf(wD, gD.y, aDy);
      }
      for (; i < deg; ++i) {
        int   s  = __shfl(sl, i);
        float w0 = __shfl(a0, i), w1 = __shfl(a1, i);
        float w  = hi ? w1 : w0;
        float2 g2 = __half22float2(*(const __half2*)&G[(size_t)s * 128 + 2 * lane]);
        aAx = fmaf(w, g2.x, aAx); aAy = fmaf(w, g2.y, aAy);
      }
    } else {
      float s0 = 0.f, s1 = 0.f;
      for (int i = lane; i < deg; i += 64) {
        int s = csr_src[beg + i];
        float2 ap = *(const float2*)&als[(size_t)s * 2];
        float v0 = ap.x + adp.x; v0 = v0 > 0.f ? v0 : NEG_SLOPE * v0;
        float v1 = ap.y + adp.y; v1 = v1 > 0.f ? v1 : NEG_SLOPE * v1;
        s0 += __expf(v0); s1 += __expf(v1);
      }
#pragma unroll
      for (int o = 1; o < 64; o <<= 1) {
        s0 += __shfl_xor(s0, o);
        s1 += __shfl_xor(s1, o);
      }
      float inv0 = 1.f / (s0 + SM_EPS);
      float inv1 = 1.f / (s1 + SM_EPS);
      bool hi = (lane >= 32);
      for (int i = 0; i < deg; ++i) {
        int s = csr_src[beg + i];
        float2 ap = *(const float2*)&als[(size_t)s * 2];
        float v0 = ap.x + adp.x; v0 = v0 > 0.f ? v0 : NEG_SLOPE * v0;
        float v1 = ap.y + adp.y; v1 = v1 > 0.f ? v1 : NEG_SLOPE * v1;
        float w = hi ? (__expf(v1) * inv1) : (__expf(v0) * inv0);
        float2 g2 = __half22float2(*(const __half2*)&G[(size_t)s * 128 + 2 * lane]);
        aAx = fmaf(w, g2.x, aAx); aAy = fmaf(w, g2.y, aAy);
      }
    }
    float accx = (aAx + aBx) + (aCx + aDx);
    float accy = (aAy + aBy) + (aCy + aDy);
    int j0 = 2 * lane;
    float2 bv = *(const float2*)&bias[j0];
    float2 mv = *(const float2*)&mean[j0];
    float2 vv = *(const float2*)&var[j0];
    float2 gv = *(const float2*)&gamma[j0];
    float2 tv = *(const float2*)&beta[j0];
    float u0 = (accx + bv.x - mv.x) * rsqrtf(vv.x + BN_EPS) * gv.x + tv.x;
    float u1 = (accy + bv.y - mv.y) * rsqrtf(vv.y + BN_EPS) * gv.y + tv.y;
    *(float2*)&out[(size_t)node * 128 + j0] = make_float2(fmaxf(u0, 0.f), fmaxf(u1, 0.f));
  }
}

// ---------- GAT aggregation (H=1, final layer, bias only) ----------
__global__ __launch_bounds__(256) void gat_agg1_k(
    const int* __restrict__ rowptr, const uint16_t* __restrict__ csr_src,
    const float* __restrict__ als, const float* __restrict__ ald,
    const __half* __restrict__ G, const float* __restrict__ bias,
    float* __restrict__ out, int n) {
  int lane = threadIdx.x & 63;
  int wid  = (blockIdx.x * blockDim.x + threadIdx.x) >> 6;
  int nw   = (gridDim.x * blockDim.x) >> 6;
  for (int node = wid; node < n; node += nw) {
    int beg = rowptr[node];
    int deg = rowptr[node + 1] - beg;
    float ad0 = ald[node];
    float aA = 0.f, aB = 0.f, aC = 0.f, aD = 0.f;
    if (deg <= 64) {
      int sl = 0;
      float p0 = 0.f;
      if (lane < deg) {
        sl = csr_src[beg + lane];
        float v0 = als[sl] + ad0;
        v0 = v0 > 0.f ? v0 : NEG_SLOPE * v0;
        p0 = __expf(v0);
      }
      float s0 = p0;
#pragma unroll
      for (int o = 1; o < 64; o <<= 1) s0 += __shfl_xor(s0, o);
      float a0 = p0 / (s0 + SM_EPS);
      int i = 0;
      for (; i + 4 <= deg; i += 4) {
        int sA = __shfl(sl, i), sB = __shfl(sl, i + 1);
        int sC = __shfl(sl, i + 2), sD = __shfl(sl, i + 3);
        float wA = __shfl(a0, i),     wB = __shfl(a0, i + 1);
        float wC = __shfl(a0, i + 2), wD = __shfl(a0, i + 3);
        float gA = __half2float(G[(size_t)sA * 64 + lane]);
        float gB = __half2float(G[(size_t)sB * 64 + lane]);
        float gC = __half2float(G[(size_t)sC * 64 + lane]);
        float gD = __half2float(G[(size_t)sD * 64 + lane]);
        aA = fmaf(wA, gA, aA); aB = fmaf(wB, gB, aB);
        aC = fmaf(wC, gC, aC); aD = fmaf(wD, gD, aD);
      }
      for (; i < deg; ++i) {
        int   s = __shfl(sl, i);
        float w = __shfl(a0, i);
        aA = fmaf(w, __half2float(G[(size_t)s * 64 + lane]), aA);
      }
    } else {
      float s0 = 0.f;
      for (int i = lane; i < deg; i += 64) {
        int s = csr_src[beg + i];
        float v0 = als[s] + ad0; v0 = v0 > 0.f ? v0 : NEG_SLOPE * v0;
        s0 += __expf(v0);
      }
#pragma unroll
      for (int o = 1; o < 64; o <<= 1) s0 += __shfl_xor(s0, o);
      float inv0 = 1.f / (s0 + SM_EPS);
      for (int i = 0; i < deg; ++i) {
        int s = csr_src[beg + i];
        float v0 = als[s] + ad0; v0 = v0 > 0.f ? v0 : NEG_SLOPE * v0;
        float w = __expf(v0) * inv0;
        aA = fmaf(w, __half2float(G[(size_t)s * 64 + lane]), aA);
      }
    }
    out[(size_t)node * 64 + lane] = ((aA + aB) + (aC + aD)) + bias[lane];
  }
}

// =======================================================================
extern "C" void kernel_launch(void* const* d_in, const int* in_sizes, int n_in,
                              void* d_out, int out_size, void* d_ws, size_t ws_size,
                              hipStream_t stream) {
  const float* x   = (const float*)d_in[0];
  const int*   ei  = (const int*)d_in[1];
  const float* W0  = (const float*)d_in[2];
  const float* as0 = (const float*)d_in[3];
  const float* ad0 = (const float*)d_in[4];
  const float* b0  = (const float*)d_in[5];
  const float* gm0 = (const float*)d_in[6];
  const float* bt0 = (const float*)d_in[7];
  const float* mu0 = (const float*)d_in[8];
  const float* vr0 = (const float*)d_in[9];
  const float* W1  = (const float*)d_in[10];
  const float* as1 = (const float*)d_in[11];
  const float* ad1 = (const float*)d_in[12];
  const float* b1  = (const float*)d_in[13];
  const float* gm1 = (const float*)d_in[14];
  const float* bt1 = (const float*)d_in[15];
  const float* mu1 = (const float*)d_in[16];
  const float* vr1 = (const float*)d_in[17];
  const float* W2  = (const float*)d_in[18];
  const float* as2 = (const float*)d_in[19];
  const float* ad2 = (const float*)d_in[20];
  const float* b2  = (const float*)d_in[21];

  int N  = in_sizes[0] / 128;
  int E  = in_sizes[1] / 2;
  int ET = E + N;
  const int* srcp = ei;
  const int* dstp = ei + E;

  char* w = (char*)d_ws;
  auto carve = [&](size_t bytes) {
    void* p = (void*)w;
    w += (bytes + 255) & ~(size_t)255;
    return p;
  };
  __half*   G      = (__half*)carve((size_t)N * 128 * 2);
  float*    Hb     = (float*)carve((size_t)N * 128 * 4);
  float*    ALS    = (float*)carve((size_t)N * 2 * 4);
  float*    ALD    = (float*)carve((size_t)N * 2 * 4);
  int*      DEG    = (int*)carve((size_t)N * 4);
  int*      INCL   = (int*)carve((size_t)N * 4);
  int*      BSUM   = (int*)carve((size_t)64 * 4);
  int*      ROWPTR = (int*)carve((size_t)(N + 1) * 4);
  int*      CURSOR = (int*)carve((size_t)N * 4);
  uint16_t* CSRSRC = (uint16_t*)carve((size_t)ET * 2);

  int egrid = min((ET + 255) / 256, 2048);
  int agrid = (N + 3) / 4;
  int nblk  = (N + 1023) / 1024;

  // ---- CSR build (graph shared by all 3 layers) ----
  hipMemsetAsync(DEG, 0, (size_t)N * 4, stream);
  deg_k<<<egrid, 256, 0, stream>>>(dstp, E, N, DEG);
  scan1_k<<<nblk, 1024, 0, stream>>>(DEG, INCL, BSUM, N);
  scan2_k<<<1, 64, 0, stream>>>(BSUM, nblk);
  scan3_k<<<(N + 255) / 256, 256, 0, stream>>>(INCL, BSUM, DEG, ROWPTR, CURSOR, N);
  csr_fill_k<<<egrid, 256, 0, stream>>>(srcp, dstp, E, N, CURSOR, CSRSRC);

  // ---------------- layer 0 ----------------
  gemm_k<128, 128, 2><<<512, 256, 0, stream>>>(x, W0, as0, ad0, G, ALS, ALD, N);
  gat_agg2_k<<<agrid, 256, 0, stream>>>(ROWPTR, CSRSRC, ALS, ALD, G, b0, gm0, bt0,
                                        mu0, vr0, Hb, N);
  // ---------------- layer 1 ----------------
  gemm_k<128, 128, 2><<<512, 256, 0, stream>>>(Hb, W1, as1, ad1, G, ALS, ALD, N);
  gat_agg2_k<<<agrid, 256, 0, stream>>>(ROWPTR, CSRSRC, ALS, ALD, G, b1, gm1, bt1,
                                        mu1, vr1, Hb, N);
  // ---------------- layer 2 ----------------
  gemm_k<128, 64, 1><<<512, 256, 0, stream>>>(Hb, W2, as2, ad2, G, ALS, ALD, N);
  gat_agg1_k<<<agrid, 256, 0, stream>>>(ROWPTR, CSRSRC, ALS, ALD, G, b2,
                                        (float*)d_out, N);
}